// Round 1
// baseline (449.773 us; speedup 1.0000x reference)
//
#include <hip/hip_runtime.h>
#include <math.h>

#define BB 64
#define HH 1024
#define SS 2048
#define VV 50257

__device__ __forceinline__ float sigf(float x){ return 1.0f/(1.0f+__expf(-x)); }

// ---------------- embedding gather: x[b][k] = emb_W[seq[b]][k] ----------------
__global__ void k_embed(const int* __restrict__ seq, const float* __restrict__ embW,
                        float* __restrict__ x){
  int b = blockIdx.x;
  int k = threadIdx.x * 4;
  const float4 v = *reinterpret_cast<const float4*>(embW + (size_t)seq[b]*HH + k);
  *reinterpret_cast<float4*>(x + (size_t)b*HH + k) = v;
}

// ---------------- generic fp32 GEMM: C[64][N] = act(A1@W1^T (+A2@W2^T) + biases)
// A: [64][K] row-major, W: [N][ldw] row-major (uses first K cols at given base).
// gridDim.y = SK split-K; direct=0 -> write partials dst[sk][64][N] (no bias/act).
__global__ __launch_bounds__(256)
void k_gemm(const float* __restrict__ A1, const float* __restrict__ W1,
            const float* __restrict__ A2, const float* __restrict__ W2,
            const float* __restrict__ bias1, const float* __restrict__ bias2,
            float* __restrict__ dst, int N, int K, int ldw, int direct, int act)
{
  __shared__ float As[64][33];
  __shared__ float Ws[128][33];
  const int tid = threadIdx.x;
  const int nb = blockIdx.x, sk = blockIdx.y, SK = gridDim.y;
  const int nmat = (A2 != nullptr) ? 2 : 1;
  const int ntiles = nmat * (K >> 5);
  const int tps = ntiles / SK;
  const int t0 = sk * tps;
  const int bg = tid & 15, ng = tid >> 4;

  float acc[4][8];
  #pragma unroll
  for (int i = 0; i < 4; ++i)
    #pragma unroll
    for (int j = 0; j < 8; ++j) acc[i][j] = 0.f;

  const int ar = tid >> 2, ac = (tid & 3) * 8;
  const int wr = tid >> 1, wc = (tid & 1) * 16;
  const int wn = nb * 128 + wr;

  for (int t = t0; t < t0 + tps; ++t) {
    const int kt = t << 5;
    const float* A; const float* W; int kk;
    if (kt < K) { A = A1; W = W1; kk = kt; } else { A = A2; W = W2; kk = kt - K; }
    {
      const float* s = A + (size_t)ar * K + kk + ac;
      float4 v0 = *(const float4*)s;
      float4 v1 = *(const float4*)(s + 4);
      As[ar][ac+0]=v0.x; As[ar][ac+1]=v0.y; As[ar][ac+2]=v0.z; As[ar][ac+3]=v0.w;
      As[ar][ac+4]=v1.x; As[ar][ac+5]=v1.y; As[ar][ac+6]=v1.z; As[ar][ac+7]=v1.w;
    }
    if (wn < N) {
      const float* s = W + (size_t)wn * ldw + kk + wc;
      float4 v0 = *(const float4*)s;
      float4 v1 = *(const float4*)(s + 4);
      float4 v2 = *(const float4*)(s + 8);
      float4 v3 = *(const float4*)(s + 12);
      Ws[wr][wc+0]=v0.x;  Ws[wr][wc+1]=v0.y;  Ws[wr][wc+2]=v0.z;  Ws[wr][wc+3]=v0.w;
      Ws[wr][wc+4]=v1.x;  Ws[wr][wc+5]=v1.y;  Ws[wr][wc+6]=v1.z;  Ws[wr][wc+7]=v1.w;
      Ws[wr][wc+8]=v2.x;  Ws[wr][wc+9]=v2.y;  Ws[wr][wc+10]=v2.z; Ws[wr][wc+11]=v2.w;
      Ws[wr][wc+12]=v3.x; Ws[wr][wc+13]=v3.y; Ws[wr][wc+14]=v3.z; Ws[wr][wc+15]=v3.w;
    }
    __syncthreads();
    #pragma unroll 8
    for (int k = 0; k < 32; ++k) {
      const float a0 = As[bg*4+0][k], a1 = As[bg*4+1][k];
      const float a2 = As[bg*4+2][k], a3 = As[bg*4+3][k];
      #pragma unroll
      for (int j = 0; j < 8; ++j) {
        const float w = Ws[ng*8+j][k];
        acc[0][j] += a0*w; acc[1][j] += a1*w; acc[2][j] += a2*w; acc[3][j] += a3*w;
      }
    }
    __syncthreads();
  }

  if (direct) {
    #pragma unroll
    for (int j = 0; j < 8; ++j) {
      const int n = nb*128 + ng*8 + j;
      if (n < N) {
        const float bsum = (bias1 ? bias1[n] : 0.f) + (bias2 ? bias2[n] : 0.f);
        #pragma unroll
        for (int i = 0; i < 4; ++i) {
          float v = acc[i][j] + bsum;
          if (act == 1) v = tanhf(v);
          dst[(size_t)(bg*4+i)*N + n] = v;
        }
      }
    }
  } else {
    #pragma unroll
    for (int j = 0; j < 8; ++j) {
      const int n = nb*128 + ng*8 + j;
      if (n < N)
        #pragma unroll
        for (int i = 0; i < 4; ++i)
          dst[((size_t)sk*64 + (bg*4+i))*N + n] = acc[i][j];
    }
  }
}

// ---------------- split-K reduce + bias + act ----------------
__global__ void k_reduce(const float* __restrict__ part, const float* __restrict__ bias1,
                         const float* __restrict__ bias2, float* __restrict__ dst,
                         int N, int SK, int act){
  size_t idx = (size_t)blockIdx.x*256 + threadIdx.x;
  if (idx >= (size_t)64*N) return;
  int b = (int)(idx / N), n = (int)(idx % N);
  float v = (bias1 ? bias1[n] : 0.f) + (bias2 ? bias2[n] : 0.f);
  for (int s = 0; s < SK; ++s) v += part[((size_t)s*64 + b)*N + n];
  if (act == 1) v = tanhf(v);
  dst[(size_t)b*N + n] = v;
}

// ---------------- LSTM pointwise (PyTorch gate order i,f,g,o) ----------------
__global__ void k_lstm(const float* __restrict__ gates, const float* __restrict__ c0,
                       float* __restrict__ h_out, float* __restrict__ c_out){
  int idx = blockIdx.x*256 + threadIdx.x;
  int b = idx >> 10, k = idx & 1023;
  const float* g = gates + (size_t)b*4096;
  float gi = g[k], gf = g[1024+k], gg = g[2048+k], go = g[3072+k];
  float c = sigf(gf)*c0[idx] + sigf(gi)*tanhf(gg);
  float h = sigf(go)*tanhf(c);
  c_out[idx] = c;
  h_out[idx] = h;
}

// ---------------- fused attention pass 1: per-(b, s-chunk) flash-style partials
__global__ __launch_bounds__(256)
void k_attn_part(const float* __restrict__ h, const float* __restrict__ enc,
                 float* __restrict__ energ, float* __restrict__ mpart,
                 float* __restrict__ lpart, float* __restrict__ ctxpart, int C){
  const int b  = blockIdx.x & 63;
  const int ch = blockIdx.x >> 6;
  const int tid = threadIdx.x;
  const int rows = SS / C;
  const int s0 = ch * rows;
  __shared__ float rbuf[4];
  const float4 hf = *(const float4*)(h + (size_t)b*HH + tid*4);
  float m = -INFINITY, l = 0.f;
  float cx = 0.f, cy = 0.f, cz = 0.f, cw = 0.f;
  for (int s = s0; s < s0 + rows; ++s) {
    const float4 ev = *(const float4*)(enc + ((size_t)s*BB + b)*HH + tid*4);
    float p = hf.x*ev.x + hf.y*ev.y + hf.z*ev.z + hf.w*ev.w;
    p += __shfl_down(p, 32); p += __shfl_down(p, 16); p += __shfl_down(p, 8);
    p += __shfl_down(p, 4);  p += __shfl_down(p, 2);  p += __shfl_down(p, 1);
    if ((tid & 63) == 0) rbuf[tid >> 6] = p;
    __syncthreads();
    const float e = rbuf[0] + rbuf[1] + rbuf[2] + rbuf[3];
    __syncthreads();
    if (tid == 0) energ[(size_t)b*SS + s] = e;
    const float mn = fmaxf(m, e);
    const float sc = __expf(m - mn);
    const float pe = __expf(e - mn);
    l = l*sc + pe;
    cx = cx*sc + pe*ev.x; cy = cy*sc + pe*ev.y;
    cz = cz*sc + pe*ev.z; cw = cw*sc + pe*ev.w;
    m = mn;
  }
  if (tid == 0) { mpart[b*C+ch] = m; lpart[b*C+ch] = l; }
  float* cp = ctxpart + ((size_t)(b*C+ch))*HH + tid*4;
  cp[0] = cx; cp[1] = cy; cp[2] = cz; cp[3] = cw;
}

// ---------------- attention combine: global softmax + context + attn output ----
__global__ void k_attn_fin(const float* __restrict__ mpart, const float* __restrict__ lpart,
                           const float* __restrict__ ctxpart, const float* __restrict__ energ,
                           float* __restrict__ ctx, float* __restrict__ attn, int C){
  const int b = blockIdx.x, tid = threadIdx.x;
  float m = -INFINITY;
  for (int c = 0; c < C; ++c) m = fmaxf(m, mpart[b*C+c]);
  float l = 0.f;
  for (int c = 0; c < C; ++c) l += lpart[b*C+c] * __expf(mpart[b*C+c] - m);
  const float inv = 1.0f / l;
  float ax = 0.f, ay = 0.f, az = 0.f, aw = 0.f;
  for (int c = 0; c < C; ++c) {
    const float w = __expf(mpart[b*C+c] - m);
    const float* cp = ctxpart + ((size_t)(b*C+c))*HH + tid*4;
    ax += w*cp[0]; ay += w*cp[1]; az += w*cp[2]; aw += w*cp[3];
  }
  float* o = ctx + (size_t)b*HH + tid*4;
  o[0] = ax*inv; o[1] = ay*inv; o[2] = az*inv; o[3] = aw*inv;
  for (int j = 0; j < 8; ++j) {
    const int s = j*256 + tid;
    attn[(size_t)b*SS + s] = __expf(energ[(size_t)b*SS + s] - m) * inv;
  }
}

extern "C" void kernel_launch(void* const* d_in, const int* in_sizes, int n_in,
                              void* d_out, int out_size, void* d_ws, size_t ws_size,
                              hipStream_t stream){
  const int*   seq  = (const int*)  d_in[0];
  const float* h0   = (const float*)d_in[1];
  const float* c0   = (const float*)d_in[2];
  const float* enc  = (const float*)d_in[3];
  const float* embW = (const float*)d_in[4];
  const float* W_ih = (const float*)d_in[5];
  const float* W_hh = (const float*)d_in[6];
  const float* b_ih = (const float*)d_in[7];
  const float* b_hh = (const float*)d_in[8];
  const float* cW   = (const float*)d_in[9];
  const float* cb   = (const float*)d_in[10];
  const float* oW   = (const float*)d_in[11];
  const float* ob   = (const float*)d_in[12];
  float* out = (float*)d_out;

  float* ws = (float*)d_ws;
  // workspace layout (floats)
  const size_t o_x = 0, o_gates = 65536, o_energ = 327680, o_ctx = 458752,
               o_concat = 524288, o_dyn = 589824;
  int C = 16, SK = 4;
  for (;;) {
    size_t need = (o_dyn + (size_t)C*128 + (size_t)C*65536 +
                   (SK > 1 ? (size_t)SK*262144 : 0)) * sizeof(float);
    if (need <= ws_size || (C == 1 && SK == 1)) break;
    if (C > 1)  C >>= 1;
    if (SK > 1) SK >>= 1;
  }
  float* x       = ws + o_x;
  float* gates   = ws + o_gates;
  float* energ   = ws + o_energ;
  float* ctx     = ws + o_ctx;
  float* conc    = ws + o_concat;
  float* mpart   = ws + o_dyn;
  float* lpart   = mpart + (size_t)64*C;
  float* ctxpart = lpart + (size_t)64*C;
  float* skpart  = ctxpart + (size_t)64*C*1024;

  const size_t o_h = 3216448, o_c = 3281984, o_attn = 3347520;

  k_embed<<<64, 256, 0, stream>>>(seq, embW, x);

  // gates = x@W_ih^T + h0@W_hh^T + b_ih + b_hh     [64 x 4096]
  {
    dim3 g(32, SK);
    if (SK > 1) {
      k_gemm<<<g, 256, 0, stream>>>(x, W_ih, h0, W_hh, nullptr, nullptr,
                                    skpart, 4096, 1024, 1024, 0, 0);
      k_reduce<<<(64*4096)/256, 256, 0, stream>>>(skpart, b_ih, b_hh, gates, 4096, SK, 0);
    } else {
      k_gemm<<<g, 256, 0, stream>>>(x, W_ih, h0, W_hh, b_ih, b_hh,
                                    gates, 4096, 1024, 1024, 1, 0);
    }
  }

  k_lstm<<<256, 256, 0, stream>>>(gates, c0, out + o_h, out + o_c);

  // fused attention (single encoder read)
  k_attn_part<<<64*C, 256, 0, stream>>>(out + o_h, enc, energ, mpart, lpart, ctxpart, C);
  k_attn_fin<<<64, 256, 0, stream>>>(mpart, lpart, ctxpart, energ, ctx, out + o_attn, C);

  // concat_out = tanh([h, ctx] @ concat_W^T + concat_b)   [64 x 1024]
  {
    dim3 g(8, SK);
    if (SK > 1) {
      k_gemm<<<g, 256, 0, stream>>>(out + o_h, cW, ctx, cW + 1024, nullptr, nullptr,
                                    skpart, 1024, 1024, 2048, 0, 0);
      k_reduce<<<(64*1024)/256, 256, 0, stream>>>(skpart, cb, nullptr, conc, 1024, SK, 1);
    } else {
      k_gemm<<<g, 256, 0, stream>>>(out + o_h, cW, ctx, cW + 1024, cb, nullptr,
                                    conc, 1024, 1024, 2048, 1, 1);
    }
  }

  // logits = concat_out @ out_W^T + out_b   [64 x 50257]
  k_gemm<<<dim3(393, 1), 256, 0, stream>>>(conc, oW, nullptr, nullptr, ob, nullptr,
                                           out, 50257, 1024, 1024, 1, 0);
}

// Round 2
// 271.614 us; speedup vs baseline: 1.6559x; 1.6559x over previous
//
#include <hip/hip_runtime.h>
#include <hip/hip_bf16.h>
#include <math.h>

#define BB 64
#define HH 1024
#define SS 2048
#define VV 50257

typedef float f32x4 __attribute__((ext_vector_type(4)));
typedef short bf16x8 __attribute__((ext_vector_type(8)));

__device__ __forceinline__ float sigf(float x){ return 1.0f/(1.0f+__expf(-x)); }
__device__ __forceinline__ short f2bf(float f){
  __hip_bfloat16 h = __float2bfloat16(f);
  return __builtin_bit_cast(short, h);
}

// ---------------- embedding gather: x[b][k] = emb_W[seq[b]][k] (fp32) --------
__global__ void k_embed(const int* __restrict__ seq, const float* __restrict__ embW,
                        float* __restrict__ x){
  int b = blockIdx.x;
  int k = threadIdx.x * 4;
  const float4 v = *reinterpret_cast<const float4*>(embW + (size_t)seq[b]*HH + k);
  *reinterpret_cast<float4*>(x + (size_t)b*HH + k) = v;
}

// ---------------- fp32 GEMM (gates only): partials dst[sk][64][N] ------------
__global__ __launch_bounds__(256)
void k_gemm(const float* __restrict__ A1, const float* __restrict__ W1,
            const float* __restrict__ A2, const float* __restrict__ W2,
            float* __restrict__ dst, int N, int K, int ldw)
{
  __shared__ float As[64][33];
  __shared__ float Ws[128][33];
  const int tid = threadIdx.x;
  const int nb = blockIdx.x, sk = blockIdx.y, SK = gridDim.y;
  const int ntiles = 2 * (K >> 5);
  const int tps = ntiles / SK;
  const int t0 = sk * tps;
  const int bg = tid & 15, ng = tid >> 4;

  float acc[4][8];
  #pragma unroll
  for (int i = 0; i < 4; ++i)
    #pragma unroll
    for (int j = 0; j < 8; ++j) acc[i][j] = 0.f;

  const int ar = tid >> 2, ac = (tid & 3) * 8;
  const int wr = tid >> 1, wc = (tid & 1) * 16;
  const int wn = nb * 128 + wr;

  for (int t = t0; t < t0 + tps; ++t) {
    const int kt = t << 5;
    const float* A; const float* W; int kk;
    if (kt < K) { A = A1; W = W1; kk = kt; } else { A = A2; W = W2; kk = kt - K; }
    {
      const float* s = A + (size_t)ar * K + kk + ac;
      float4 v0 = *(const float4*)s;
      float4 v1 = *(const float4*)(s + 4);
      As[ar][ac+0]=v0.x; As[ar][ac+1]=v0.y; As[ar][ac+2]=v0.z; As[ar][ac+3]=v0.w;
      As[ar][ac+4]=v1.x; As[ar][ac+5]=v1.y; As[ar][ac+6]=v1.z; As[ar][ac+7]=v1.w;
    }
    if (wn < N) {
      const float* s = W + (size_t)wn * ldw + kk + wc;
      float4 v0 = *(const float4*)s;
      float4 v1 = *(const float4*)(s + 4);
      float4 v2 = *(const float4*)(s + 8);
      float4 v3 = *(const float4*)(s + 12);
      Ws[wr][wc+0]=v0.x;  Ws[wr][wc+1]=v0.y;  Ws[wr][wc+2]=v0.z;  Ws[wr][wc+3]=v0.w;
      Ws[wr][wc+4]=v1.x;  Ws[wr][wc+5]=v1.y;  Ws[wr][wc+6]=v1.z;  Ws[wr][wc+7]=v1.w;
      Ws[wr][wc+8]=v2.x;  Ws[wr][wc+9]=v2.y;  Ws[wr][wc+10]=v2.z; Ws[wr][wc+11]=v2.w;
      Ws[wr][wc+12]=v3.x; Ws[wr][wc+13]=v3.y; Ws[wr][wc+14]=v3.z; Ws[wr][wc+15]=v3.w;
    }
    __syncthreads();
    #pragma unroll 8
    for (int k = 0; k < 32; ++k) {
      const float a0 = As[bg*4+0][k], a1 = As[bg*4+1][k];
      const float a2 = As[bg*4+2][k], a3 = As[bg*4+3][k];
      #pragma unroll
      for (int j = 0; j < 8; ++j) {
        const float w = Ws[ng*8+j][k];
        acc[0][j] += a0*w; acc[1][j] += a1*w; acc[2][j] += a2*w; acc[3][j] += a3*w;
      }
    }
    __syncthreads();
  }

  #pragma unroll
  for (int j = 0; j < 8; ++j) {
    const int n = nb*128 + ng*8 + j;
    if (n < N)
      #pragma unroll
      for (int i = 0; i < 4; ++i)
        dst[((size_t)sk*64 + (bg*4+i))*N + n] = acc[i][j];
  }
}

// ---------------- streaming bf16 MFMA GEMM: D[64][N] = A_bf16 @ W_fp32^T -----
// A: bf16 [64][Ktot] (lda elems). W1/W2 fp32 [N][ldw]; k>=K1 -> W2 at (k-K1).
// direct=1: D = act(acc + bias) -> dst(fp32) and/or dstb(bf16)
// direct=0: partials dst[sk][64][N] (fp32)
__global__ __launch_bounds__(256)
void k_mfma(const short* __restrict__ A, int lda,
            const float* __restrict__ W1, const float* __restrict__ W2,
            int K1, int ldw, const float* __restrict__ bias,
            float* __restrict__ dst, short* __restrict__ dstb,
            int N, int Ktot, int direct, int act)
{
  const int tid  = threadIdx.x;
  const int wave = tid >> 6, lane = tid & 63;
  const int nb = blockIdx.x, sk = blockIdx.y, SK = gridDim.y;
  const int ksteps = Ktot >> 5;
  const int kps = ksteps / SK;
  const int k0 = sk * kps;
  const int n0 = nb*128 + wave*32;
  const int r = lane & 15, g = lane >> 4;

  f32x4 acc[4][2] = {};

  for (int ks = k0; ks < k0 + kps; ++ks) {
    const int kk = (ks << 5) + g*8;
    bf16x8 af[4];
    #pragma unroll
    for (int mf = 0; mf < 4; ++mf)
      af[mf] = *(const bf16x8*)(A + (size_t)(mf*16 + r)*lda + kk);
    #pragma unroll
    for (int nf = 0; nf < 2; ++nf) {
      const int n = n0 + nf*16 + r;
      bf16x8 bfr = {};
      if (n < N) {
        const float* wp = (kk < K1) ? (W1 + (size_t)n*ldw + kk)
                                    : (W2 + (size_t)n*ldw + (kk - K1));
        float4 w0 = *(const float4*)wp;
        float4 w1 = *(const float4*)(wp + 4);
        bfr[0]=f2bf(w0.x); bfr[1]=f2bf(w0.y); bfr[2]=f2bf(w0.z); bfr[3]=f2bf(w0.w);
        bfr[4]=f2bf(w1.x); bfr[5]=f2bf(w1.y); bfr[6]=f2bf(w1.z); bfr[7]=f2bf(w1.w);
      }
      #pragma unroll
      for (int mf = 0; mf < 4; ++mf)
        acc[mf][nf] = __builtin_amdgcn_mfma_f32_16x16x32_bf16(af[mf], bfr, acc[mf][nf], 0, 0, 0);
    }
  }

  // D layout: row = mf*16 + g*4 + j, col = n0 + nf*16 + r
  if (direct) {
    #pragma unroll
    for (int nf = 0; nf < 2; ++nf) {
      const int n = n0 + nf*16 + r;
      if (n < N) {
        const float bv = bias ? bias[n] : 0.f;
        #pragma unroll
        for (int mf = 0; mf < 4; ++mf)
          #pragma unroll
          for (int j = 0; j < 4; ++j) {
            float v = acc[mf][nf][j] + bv;
            if (act == 1) v = tanhf(v);
            const int row = mf*16 + g*4 + j;
            if (dst)  dst[(size_t)row*N + n] = v;
            if (dstb) dstb[(size_t)row*N + n] = f2bf(v);
          }
      }
    }
  } else {
    #pragma unroll
    for (int nf = 0; nf < 2; ++nf) {
      const int n = n0 + nf*16 + r;
      if (n < N)
        #pragma unroll
        for (int mf = 0; mf < 4; ++mf)
          #pragma unroll
          for (int j = 0; j < 4; ++j)
            dst[((size_t)sk*64 + (mf*16 + g*4 + j))*N + n] = acc[mf][nf][j];
    }
  }
}

// ---------------- split-K reduce + bias + act, fp32 and/or bf16 out ----------
__global__ void k_reduce(const float* __restrict__ part, const float* __restrict__ bias1,
                         const float* __restrict__ bias2, float* __restrict__ dst,
                         short* __restrict__ dstb, int N, int SK, int act){
  size_t idx = (size_t)blockIdx.x*256 + threadIdx.x;
  if (idx >= (size_t)64*N) return;
  int b = (int)(idx / N), n = (int)(idx % N);
  float v = (bias1 ? bias1[n] : 0.f) + (bias2 ? bias2[n] : 0.f);
  for (int s = 0; s < SK; ++s) v += part[((size_t)s*64 + b)*N + n];
  if (act == 1) v = tanhf(v);
  if (dst)  dst[(size_t)b*N + n] = v;
  if (dstb) dstb[(size_t)b*N + n] = f2bf(v);
}

// ---------------- LSTM pointwise; also writes h as bf16 into concA[:,0:1024] -
__global__ void k_lstm(const float* __restrict__ gates, const float* __restrict__ c0,
                       float* __restrict__ h_out, float* __restrict__ c_out,
                       short* __restrict__ concA){
  int idx = blockIdx.x*256 + threadIdx.x;
  int b = idx >> 10, k = idx & 1023;
  const float* g = gates + (size_t)b*4096;
  float gi = g[k], gf = g[1024+k], gg = g[2048+k], go = g[3072+k];
  float c = sigf(gf)*c0[idx] + sigf(gi)*tanhf(gg);
  float h = sigf(go)*tanhf(c);
  c_out[idx] = c;
  h_out[idx] = h;
  concA[(size_t)b*2048 + k] = f2bf(h);
}

// ---------------- attention pass 1: wave-per-s, no barriers in loop ----------
__global__ __launch_bounds__(256)
void k_attn_part(const float* __restrict__ h, const float* __restrict__ enc,
                 float* __restrict__ energ, float* __restrict__ mpart,
                 float* __restrict__ lpart, float* __restrict__ ctxpart, int C){
  const int b  = blockIdx.x & 63;
  const int ch = blockIdx.x >> 6;
  const int wave = threadIdx.x >> 6;
  const int lane = threadIdx.x & 63;
  const int rows = SS / C;
  const int s0 = ch * rows;

  float4 hv0, hv1, hv2, hv3;
  {
    const float* hb = h + (size_t)b*HH + lane*16;
    hv0 = *(const float4*)(hb);   hv1 = *(const float4*)(hb+4);
    hv2 = *(const float4*)(hb+8); hv3 = *(const float4*)(hb+12);
  }
  float m = -INFINITY, l = 0.f;
  float cacc[16];
  #pragma unroll
  for (int j = 0; j < 16; ++j) cacc[j] = 0.f;

  for (int s = s0 + wave; s < s0 + rows; s += 4) {
    const float* ep = enc + ((size_t)s*BB + b)*HH + lane*16;
    const float4 e0 = *(const float4*)(ep);
    const float4 e1 = *(const float4*)(ep+4);
    const float4 e2 = *(const float4*)(ep+8);
    const float4 e3 = *(const float4*)(ep+12);
    float p = hv0.x*e0.x + hv0.y*e0.y + hv0.z*e0.z + hv0.w*e0.w
            + hv1.x*e1.x + hv1.y*e1.y + hv1.z*e1.z + hv1.w*e1.w
            + hv2.x*e2.x + hv2.y*e2.y + hv2.z*e2.z + hv2.w*e2.w
            + hv3.x*e3.x + hv3.y*e3.y + hv3.z*e3.z + hv3.w*e3.w;
    p += __shfl_xor(p, 1);  p += __shfl_xor(p, 2);  p += __shfl_xor(p, 4);
    p += __shfl_xor(p, 8);  p += __shfl_xor(p, 16); p += __shfl_xor(p, 32);
    if (lane == 0) energ[(size_t)b*SS + s] = p;
    const float mn = fmaxf(m, p);
    const float sc = __expf(m - mn);
    const float pe = __expf(p - mn);
    l = l*sc + pe;
    cacc[0]=cacc[0]*sc+pe*e0.x;  cacc[1]=cacc[1]*sc+pe*e0.y;
    cacc[2]=cacc[2]*sc+pe*e0.z;  cacc[3]=cacc[3]*sc+pe*e0.w;
    cacc[4]=cacc[4]*sc+pe*e1.x;  cacc[5]=cacc[5]*sc+pe*e1.y;
    cacc[6]=cacc[6]*sc+pe*e1.z;  cacc[7]=cacc[7]*sc+pe*e1.w;
    cacc[8]=cacc[8]*sc+pe*e2.x;  cacc[9]=cacc[9]*sc+pe*e2.y;
    cacc[10]=cacc[10]*sc+pe*e2.z; cacc[11]=cacc[11]*sc+pe*e2.w;
    cacc[12]=cacc[12]*sc+pe*e3.x; cacc[13]=cacc[13]*sc+pe*e3.y;
    cacc[14]=cacc[14]*sc+pe*e3.z; cacc[15]=cacc[15]*sc+pe*e3.w;
    m = mn;
  }

  // cross-wave combine (once per block)
  __shared__ float sm[4], sl[4];
  __shared__ float sctx[4][1024];
  if (lane == 0) { sm[wave] = m; sl[wave] = l; }
  __syncthreads();
  const float mg = fmaxf(fmaxf(sm[0], sm[1]), fmaxf(sm[2], sm[3]));
  const float lg = sl[0]*__expf(sm[0]-mg) + sl[1]*__expf(sm[1]-mg)
                 + sl[2]*__expf(sm[2]-mg) + sl[3]*__expf(sm[3]-mg);
  const float scw = __expf(m - mg);
  #pragma unroll
  for (int j = 0; j < 16; ++j) sctx[wave][lane*16 + j] = cacc[j]*scw;
  __syncthreads();
  const int d = threadIdx.x * 4;
  const float4 a0 = *(const float4*)&sctx[0][d];
  const float4 a1 = *(const float4*)&sctx[1][d];
  const float4 a2 = *(const float4*)&sctx[2][d];
  const float4 a3 = *(const float4*)&sctx[3][d];
  float4 rr;
  rr.x = a0.x+a1.x+a2.x+a3.x; rr.y = a0.y+a1.y+a2.y+a3.y;
  rr.z = a0.z+a1.z+a2.z+a3.z; rr.w = a0.w+a1.w+a2.w+a3.w;
  *(float4*)(ctxpart + ((size_t)(b*C + ch))*HH + d) = rr;
  if (threadIdx.x == 0) { mpart[b*C+ch] = mg; lpart[b*C+ch] = lg; }
}

// ---------------- attention combine + ctx bf16 into concA[:,1024:2048] -------
__global__ void k_attn_fin(const float* __restrict__ mpart, const float* __restrict__ lpart,
                           const float* __restrict__ ctxpart, const float* __restrict__ energ,
                           float* __restrict__ ctx, float* __restrict__ attn,
                           short* __restrict__ concA, int C){
  const int b = blockIdx.x, tid = threadIdx.x;
  float m = -INFINITY;
  for (int c = 0; c < C; ++c) m = fmaxf(m, mpart[b*C+c]);
  float l = 0.f;
  for (int c = 0; c < C; ++c) l += lpart[b*C+c] * __expf(mpart[b*C+c] - m);
  const float inv = 1.0f / l;
  float ax = 0.f, ay = 0.f, az = 0.f, aw = 0.f;
  for (int c = 0; c < C; ++c) {
    const float w = __expf(mpart[b*C+c] - m);
    const float* cp = ctxpart + ((size_t)(b*C+c))*HH + tid*4;
    ax += w*cp[0]; ay += w*cp[1]; az += w*cp[2]; aw += w*cp[3];
  }
  ax *= inv; ay *= inv; az *= inv; aw *= inv;
  float* o = ctx + (size_t)b*HH + tid*4;
  o[0] = ax; o[1] = ay; o[2] = az; o[3] = aw;
  short* ca = concA + (size_t)b*2048 + 1024 + tid*4;
  ca[0] = f2bf(ax); ca[1] = f2bf(ay); ca[2] = f2bf(az); ca[3] = f2bf(aw);
  for (int j = 0; j < 8; ++j) {
    const int s = j*256 + tid;
    attn[(size_t)b*SS + s] = __expf(energ[(size_t)b*SS + s] - m) * inv;
  }
}

extern "C" void kernel_launch(void* const* d_in, const int* in_sizes, int n_in,
                              void* d_out, int out_size, void* d_ws, size_t ws_size,
                              hipStream_t stream){
  const int*   seq  = (const int*)  d_in[0];
  const float* h0   = (const float*)d_in[1];
  const float* c0   = (const float*)d_in[2];
  const float* enc  = (const float*)d_in[3];
  const float* embW = (const float*)d_in[4];
  const float* W_ih = (const float*)d_in[5];
  const float* W_hh = (const float*)d_in[6];
  const float* b_ih = (const float*)d_in[7];
  const float* b_hh = (const float*)d_in[8];
  const float* cW   = (const float*)d_in[9];
  const float* cb   = (const float*)d_in[10];
  const float* oW   = (const float*)d_in[11];
  const float* ob   = (const float*)d_in[12];
  float* out = (float*)d_out;

  float* ws = (float*)d_ws;
  // fixed ws layout (float offsets)
  const size_t o_x = 0, o_gates = 65536, o_energ = 327680, o_ctx = 458752,
               o_concA = 524288, o_concB = 589824, o_dyn = 622592;
  const size_t SKPART = 4194304;  // 16*64*4096 floats (gates partials, reused by concat)
  int C = 32;
  for (;;) {
    size_t need = (o_dyn + (size_t)C*128 + (size_t)C*65536 + SKPART) * sizeof(float);
    if (need <= ws_size || C == 1) break;
    C >>= 1;
  }
  float* x       = ws + o_x;
  float* gates   = ws + o_gates;
  float* energ   = ws + o_energ;
  float* ctx     = ws + o_ctx;
  short* concA   = (short*)(ws + o_concA);   // bf16 [64][2048]
  short* concB   = (short*)(ws + o_concB);   // bf16 [64][1024]
  float* mpart   = ws + o_dyn;
  float* lpart   = mpart + (size_t)64*C;
  float* ctxpart = lpart + (size_t)64*C;
  float* skpart  = ctxpart + (size_t)64*C*1024;

  const size_t o_h = 3216448, o_c = 3281984, o_attn = 3347520;

  k_embed<<<64, 256, 0, stream>>>(seq, embW, x);

  // gates = x@W_ih^T + h0@W_hh^T + b_ih + b_hh   (fp32, split-K 16)
  k_gemm<<<dim3(32,16), 256, 0, stream>>>(x, W_ih, h0, W_hh, skpart, 4096, 1024, 1024);
  k_reduce<<<1024, 256, 0, stream>>>(skpart, b_ih, b_hh, gates, nullptr, 4096, 16, 0);

  k_lstm<<<256, 256, 0, stream>>>(gates, c0, out + o_h, out + o_c, concA);

  // fused attention (single encoder read)
  k_attn_part<<<64*C, 256, 0, stream>>>(out + o_h, enc, energ, mpart, lpart, ctxpart, C);
  k_attn_fin<<<64, 256, 0, stream>>>(mpart, lpart, ctxpart, energ, ctx,
                                     out + o_attn, concA, C);

  // concat_out = tanh([h,ctx] @ cW^T + cb) -> bf16 (MFMA, split-K 32)
  k_mfma<<<dim3(8,32), 256, 0, stream>>>(concA, 2048, cW, nullptr, 2048, 2048,
                                         nullptr, skpart, nullptr, 1024, 2048, 0, 0);
  k_reduce<<<256, 256, 0, stream>>>(skpart, cb, nullptr, nullptr, concB, 1024, 32, 1);

  // logits = concat_out @ out_W^T + out_b   (streaming MFMA, memory-bound)
  k_mfma<<<dim3(393,1), 256, 0, stream>>>(concB, 1024, oW, nullptr, 1024, 1024,
                                          ob, out, nullptr, 50257, 1024, 1, 0);
}

// Round 3
// 267.374 us; speedup vs baseline: 1.6822x; 1.0159x over previous
//
#include <hip/hip_runtime.h>
#include <hip/hip_bf16.h>
#include <math.h>

#define BB 64
#define HH 1024
#define SS 2048
#define VV 50257

typedef float f32x4 __attribute__((ext_vector_type(4)));
typedef short bf16x8 __attribute__((ext_vector_type(8)));

__device__ __forceinline__ float sigf(float x){ return 1.0f/(1.0f+__expf(-x)); }
__device__ __forceinline__ short f2bf(float f){
  __hip_bfloat16 h = __float2bfloat16(f);
  return __builtin_bit_cast(short, h);
}

// ---------------- gates GEMM (fp32, embed fused): partials dst[sk][64][4096] --
__global__ __launch_bounds__(256)
void k_gates(const int* __restrict__ seq, const float* __restrict__ embW,
             const float* __restrict__ h0,
             const float* __restrict__ W_ih, const float* __restrict__ W_hh,
             float* __restrict__ dst)
{
  __shared__ float As[64][33];
  __shared__ float Ws[128][33];
  const int tid = threadIdx.x;
  const int nb = blockIdx.x, sk = blockIdx.y, SK = gridDim.y;
  const int tps = 64 / SK;          // 64 k-tiles of 32 over both matrices
  const int t0 = sk * tps;
  const int bg = tid & 15, ng = tid >> 4;

  float acc[4][8];
  #pragma unroll
  for (int i = 0; i < 4; ++i)
    #pragma unroll
    for (int j = 0; j < 8; ++j) acc[i][j] = 0.f;

  const int ar = tid >> 2, ac = (tid & 3) * 8;
  const int wr = tid >> 1, wc = (tid & 1) * 16;
  const int wn = nb * 128 + wr;
  const int erow = seq[ar];

  for (int t = t0; t < t0 + tps; ++t) {
    const int kt = t << 5;
    const float* abase; const float* wbase;
    if (kt < 1024) {
      abase = embW + (size_t)erow*1024 + kt;
      wbase = W_ih + (size_t)wn*1024 + kt;
    } else {
      abase = h0 + (size_t)ar*1024 + (kt - 1024);
      wbase = W_hh + (size_t)wn*1024 + (kt - 1024);
    }
    {
      const float* s = abase + ac;
      float4 v0 = *(const float4*)s;
      float4 v1 = *(const float4*)(s + 4);
      As[ar][ac+0]=v0.x; As[ar][ac+1]=v0.y; As[ar][ac+2]=v0.z; As[ar][ac+3]=v0.w;
      As[ar][ac+4]=v1.x; As[ar][ac+5]=v1.y; As[ar][ac+6]=v1.z; As[ar][ac+7]=v1.w;
    }
    {
      const float* s = wbase + wc;
      float4 v0 = *(const float4*)s;
      float4 v1 = *(const float4*)(s + 4);
      float4 v2 = *(const float4*)(s + 8);
      float4 v3 = *(const float4*)(s + 12);
      Ws[wr][wc+0]=v0.x;  Ws[wr][wc+1]=v0.y;  Ws[wr][wc+2]=v0.z;  Ws[wr][wc+3]=v0.w;
      Ws[wr][wc+4]=v1.x;  Ws[wr][wc+5]=v1.y;  Ws[wr][wc+6]=v1.z;  Ws[wr][wc+7]=v1.w;
      Ws[wr][wc+8]=v2.x;  Ws[wr][wc+9]=v2.y;  Ws[wr][wc+10]=v2.z; Ws[wr][wc+11]=v2.w;
      Ws[wr][wc+12]=v3.x; Ws[wr][wc+13]=v3.y; Ws[wr][wc+14]=v3.z; Ws[wr][wc+15]=v3.w;
    }
    __syncthreads();
    #pragma unroll 8
    for (int k = 0; k < 32; ++k) {
      const float a0 = As[bg*4+0][k], a1 = As[bg*4+1][k];
      const float a2 = As[bg*4+2][k], a3 = As[bg*4+3][k];
      #pragma unroll
      for (int j = 0; j < 8; ++j) {
        const float w = Ws[ng*8+j][k];
        acc[0][j] += a0*w; acc[1][j] += a1*w; acc[2][j] += a2*w; acc[3][j] += a3*w;
      }
    }
    __syncthreads();
  }

  #pragma unroll
  for (int j = 0; j < 8; ++j) {
    const int n = nb*128 + ng*8 + j;
    #pragma unroll
    for (int i = 0; i < 4; ++i)
      dst[((size_t)sk*64 + (bg*4+i))*4096 + n] = acc[i][j];
  }
}

// -------- fused split-K reduce + bias + LSTM pointwise -> h, c, concA[:, :1024]
__global__ void k_rlstm(const float* __restrict__ part, const float* __restrict__ b_ih,
                        const float* __restrict__ b_hh, const float* __restrict__ c0,
                        float* __restrict__ h_out, float* __restrict__ c_out,
                        short* __restrict__ concA, int SK){
  int idx = blockIdx.x*256 + threadIdx.x;    // 64*1024
  int b = idx >> 10, k = idx & 1023;
  float gi = b_ih[k]      + b_hh[k];
  float gf = b_ih[1024+k] + b_hh[1024+k];
  float gg = b_ih[2048+k] + b_hh[2048+k];
  float go = b_ih[3072+k] + b_hh[3072+k];
  const float* p = part + (size_t)b*4096 + k;
  for (int s = 0; s < SK; ++s) {
    const float* ps = p + (size_t)s*64*4096;
    gi += ps[0]; gf += ps[1024]; gg += ps[2048]; go += ps[3072];
  }
  float c = sigf(gf)*c0[idx] + sigf(gi)*tanhf(gg);
  float h = sigf(go)*tanhf(c);
  c_out[idx] = c;
  h_out[idx] = h;
  concA[(size_t)b*2048 + k] = f2bf(h);
}

// ---------------- streaming bf16 MFMA GEMM (concat): partials dst[sk][64][N] --
__global__ __launch_bounds__(256)
void k_mfma(const short* __restrict__ A, int lda,
            const float* __restrict__ W1, int ldw,
            float* __restrict__ dst, int N, int Ktot)
{
  const int tid  = threadIdx.x;
  const int wave = tid >> 6, lane = tid & 63;
  const int nb = blockIdx.x, sk = blockIdx.y, SK = gridDim.y;
  const int ksteps = Ktot >> 5;
  const int kps = ksteps / SK;
  const int k0 = sk * kps;
  const int n0 = nb*128 + wave*32;
  const int r = lane & 15, g = lane >> 4;

  f32x4 acc[4][2] = {};

  for (int ks = k0; ks < k0 + kps; ++ks) {
    const int kk = (ks << 5) + g*8;
    bf16x8 af[4];
    #pragma unroll
    for (int mf = 0; mf < 4; ++mf)
      af[mf] = *(const bf16x8*)(A + (size_t)(mf*16 + r)*lda + kk);
    #pragma unroll
    for (int nf = 0; nf < 2; ++nf) {
      const int n = n0 + nf*16 + r;
      const float* wp = W1 + (size_t)n*ldw + kk;
      float4 w0 = *(const float4*)wp;
      float4 w1 = *(const float4*)(wp + 4);
      bf16x8 bfr;
      bfr[0]=f2bf(w0.x); bfr[1]=f2bf(w0.y); bfr[2]=f2bf(w0.z); bfr[3]=f2bf(w0.w);
      bfr[4]=f2bf(w1.x); bfr[5]=f2bf(w1.y); bfr[6]=f2bf(w1.z); bfr[7]=f2bf(w1.w);
      #pragma unroll
      for (int mf = 0; mf < 4; ++mf)
        acc[mf][nf] = __builtin_amdgcn_mfma_f32_16x16x32_bf16(af[mf], bfr, acc[mf][nf], 0, 0, 0);
    }
  }

  #pragma unroll
  for (int nf = 0; nf < 2; ++nf) {
    const int n = n0 + nf*16 + r;
    #pragma unroll
    for (int mf = 0; mf < 4; ++mf)
      #pragma unroll
      for (int j = 0; j < 4; ++j)
        dst[((size_t)sk*64 + (mf*16 + g*4 + j))*N + n] = acc[mf][nf][j];
  }
}

// ---------------- split-K reduce + bias + tanh -> bf16 ------------------------
__global__ void k_reduce(const float* __restrict__ part, const float* __restrict__ bias,
                         short* __restrict__ dstb, int N, int SK){
  size_t idx = (size_t)blockIdx.x*256 + threadIdx.x;
  if (idx >= (size_t)64*N) return;
  int b = (int)(idx / N), n = (int)(idx % N);
  float v = bias[n];
  for (int s = 0; s < SK; ++s) v += part[((size_t)s*64 + b)*N + n];
  dstb[(size_t)b*N + n] = f2bf(tanhf(v));
}

// ---------------- logits: D[64][50257] = A_bf16[64][1024] @ oW_fp32^T + ob -----
__global__ __launch_bounds__(256)
void k_logits(const short* __restrict__ A, const float* __restrict__ W,
              const float* __restrict__ bias, float* __restrict__ out)
{
  const int tid = threadIdx.x;
  const int wave = tid >> 6, lane = tid & 63;
  const int r = lane & 15, g = lane >> 4;
  const int n0 = blockIdx.x*128 + wave*32;
  const int nA = n0 + r, nB = n0 + 16 + r;
  const float* wA = W + (size_t)(nA < VV ? nA : 0)*1024;
  const float* wB = W + (size_t)(nB < VV ? nB : 0)*1024;
  const short* A0 = A + (size_t)r*1024 + g*8;   // + ks*32 per step

  f32x4 acc[4][2] = {};

  bf16x8 a0,a1,a2,a3; float4 u0,u1,v0,v1;
  {
    const int kk = g*8;
    a0 = *(const bf16x8*)(A0);
    a1 = *(const bf16x8*)(A0 + 16*1024);
    a2 = *(const bf16x8*)(A0 + 32*1024);
    a3 = *(const bf16x8*)(A0 + 48*1024);
    u0 = *(const float4*)(wA + kk); u1 = *(const float4*)(wA + kk + 4);
    v0 = *(const float4*)(wB + kk); v1 = *(const float4*)(wB + kk + 4);
  }

  #pragma unroll
  for (int ks = 0; ks < 32; ++ks) {
    bf16x8 ca0=a0, ca1=a1, ca2=a2, ca3=a3;
    float4 cu0=u0, cu1=u1, cv0=v0, cv1=v1;
    if (ks < 31) {
      const int kk = (ks+1)*32 + g*8;
      a0 = *(const bf16x8*)(A0 + (ks+1)*32);
      a1 = *(const bf16x8*)(A0 + 16*1024 + (ks+1)*32);
      a2 = *(const bf16x8*)(A0 + 32*1024 + (ks+1)*32);
      a3 = *(const bf16x8*)(A0 + 48*1024 + (ks+1)*32);
      u0 = *(const float4*)(wA + kk); u1 = *(const float4*)(wA + kk + 4);
      v0 = *(const float4*)(wB + kk); v1 = *(const float4*)(wB + kk + 4);
    }
    bf16x8 bA, bB;
    bA[0]=f2bf(cu0.x); bA[1]=f2bf(cu0.y); bA[2]=f2bf(cu0.z); bA[3]=f2bf(cu0.w);
    bA[4]=f2bf(cu1.x); bA[5]=f2bf(cu1.y); bA[6]=f2bf(cu1.z); bA[7]=f2bf(cu1.w);
    bB[0]=f2bf(cv0.x); bB[1]=f2bf(cv0.y); bB[2]=f2bf(cv0.z); bB[3]=f2bf(cv0.w);
    bB[4]=f2bf(cv1.x); bB[5]=f2bf(cv1.y); bB[6]=f2bf(cv1.z); bB[7]=f2bf(cv1.w);
    acc[0][0] = __builtin_amdgcn_mfma_f32_16x16x32_bf16(ca0, bA, acc[0][0], 0,0,0);
    acc[1][0] = __builtin_amdgcn_mfma_f32_16x16x32_bf16(ca1, bA, acc[1][0], 0,0,0);
    acc[2][0] = __builtin_amdgcn_mfma_f32_16x16x32_bf16(ca2, bA, acc[2][0], 0,0,0);
    acc[3][0] = __builtin_amdgcn_mfma_f32_16x16x32_bf16(ca3, bA, acc[3][0], 0,0,0);
    acc[0][1] = __builtin_amdgcn_mfma_f32_16x16x32_bf16(ca0, bB, acc[0][1], 0,0,0);
    acc[1][1] = __builtin_amdgcn_mfma_f32_16x16x32_bf16(ca1, bB, acc[1][1], 0,0,0);
    acc[2][1] = __builtin_amdgcn_mfma_f32_16x16x32_bf16(ca2, bB, acc[2][1], 0,0,0);
    acc[3][1] = __builtin_amdgcn_mfma_f32_16x16x32_bf16(ca3, bB, acc[3][1], 0,0,0);
  }

  #pragma unroll
  for (int nf = 0; nf < 2; ++nf) {
    const int n = n0 + nf*16 + r;
    if (n < VV) {
      const float bv = bias[n];
      #pragma unroll
      for (int mf = 0; mf < 4; ++mf)
        #pragma unroll
        for (int j = 0; j < 4; ++j)
          out[(size_t)(mf*16 + g*4 + j)*VV + n] = acc[mf][nf][j] + bv;
    }
  }
}

// ---------------- attention pass 1: wave-per-2-rows, no barriers in loop ------
__global__ __launch_bounds__(256)
void k_attn_part(const float* __restrict__ h, const float* __restrict__ enc,
                 float* __restrict__ energ, float* __restrict__ mpart,
                 float* __restrict__ lpart, float* __restrict__ ctxpart, int C){
  const int b  = blockIdx.x & 63;
  const int ch = blockIdx.x >> 6;
  const int wave = threadIdx.x >> 6;
  const int lane = threadIdx.x & 63;
  const int rows = SS / C;
  const int rpw  = rows >> 2;
  const int sw = ch*rows + wave*rpw;

  float4 hv0, hv1, hv2, hv3;
  {
    const float* hb = h + (size_t)b*HH + lane*16;
    hv0 = *(const float4*)(hb);   hv1 = *(const float4*)(hb+4);
    hv2 = *(const float4*)(hb+8); hv3 = *(const float4*)(hb+12);
  }
  float m = -INFINITY, l = 0.f;
  float cacc[16];
  #pragma unroll
  for (int j = 0; j < 16; ++j) cacc[j] = 0.f;

  for (int i = 0; i < rpw; i += 2) {
    const float* ep = enc + ((size_t)(sw+i)*BB + b)*HH + lane*16;
    const float* fp = ep + (size_t)BB*HH;
    const float4 e0 = *(const float4*)(ep);
    const float4 e1 = *(const float4*)(ep+4);
    const float4 e2 = *(const float4*)(ep+8);
    const float4 e3 = *(const float4*)(ep+12);
    const float4 f0 = *(const float4*)(fp);
    const float4 f1 = *(const float4*)(fp+4);
    const float4 f2 = *(const float4*)(fp+8);
    const float4 f3 = *(const float4*)(fp+12);
    float p = hv0.x*e0.x + hv0.y*e0.y + hv0.z*e0.z + hv0.w*e0.w
            + hv1.x*e1.x + hv1.y*e1.y + hv1.z*e1.z + hv1.w*e1.w
            + hv2.x*e2.x + hv2.y*e2.y + hv2.z*e2.z + hv2.w*e2.w
            + hv3.x*e3.x + hv3.y*e3.y + hv3.z*e3.z + hv3.w*e3.w;
    float q = hv0.x*f0.x + hv0.y*f0.y + hv0.z*f0.z + hv0.w*f0.w
            + hv1.x*f1.x + hv1.y*f1.y + hv1.z*f1.z + hv1.w*f1.w
            + hv2.x*f2.x + hv2.y*f2.y + hv2.z*f2.z + hv2.w*f2.w
            + hv3.x*f3.x + hv3.y*f3.y + hv3.z*f3.z + hv3.w*f3.w;
    p += __shfl_xor(p, 1);  q += __shfl_xor(q, 1);
    p += __shfl_xor(p, 2);  q += __shfl_xor(q, 2);
    p += __shfl_xor(p, 4);  q += __shfl_xor(q, 4);
    p += __shfl_xor(p, 8);  q += __shfl_xor(q, 8);
    p += __shfl_xor(p, 16); q += __shfl_xor(q, 16);
    p += __shfl_xor(p, 32); q += __shfl_xor(q, 32);
    if (lane == 0) {
      float2 pq; pq.x = p; pq.y = q;
      *(float2*)(energ + (size_t)b*SS + sw + i) = pq;
    }
    const float mn = fmaxf(fmaxf(m, p), q);
    const float sc = __expf(m - mn);
    const float pe = __expf(p - mn);
    const float qe = __expf(q - mn);
    l = l*sc + pe + qe;
    cacc[0] = cacc[0]*sc + pe*e0.x + qe*f0.x;
    cacc[1] = cacc[1]*sc + pe*e0.y + qe*f0.y;
    cacc[2] = cacc[2]*sc + pe*e0.z + qe*f0.z;
    cacc[3] = cacc[3]*sc + pe*e0.w + qe*f0.w;
    cacc[4] = cacc[4]*sc + pe*e1.x + qe*f1.x;
    cacc[5] = cacc[5]*sc + pe*e1.y + qe*f1.y;
    cacc[6] = cacc[6]*sc + pe*e1.z + qe*f1.z;
    cacc[7] = cacc[7]*sc + pe*e1.w + qe*f1.w;
    cacc[8] = cacc[8]*sc + pe*e2.x + qe*f2.x;
    cacc[9] = cacc[9]*sc + pe*e2.y + qe*f2.y;
    cacc[10] = cacc[10]*sc + pe*e2.z + qe*f2.z;
    cacc[11] = cacc[11]*sc + pe*e2.w + qe*f2.w;
    cacc[12] = cacc[12]*sc + pe*e3.x + qe*f3.x;
    cacc[13] = cacc[13]*sc + pe*e3.y + qe*f3.y;
    cacc[14] = cacc[14]*sc + pe*e3.z + qe*f3.z;
    cacc[15] = cacc[15]*sc + pe*e3.w + qe*f3.w;
    m = mn;
  }

  __shared__ float sm[4], sl[4];
  __shared__ float sctx[4][1024];
  if (lane == 0) { sm[wave] = m; sl[wave] = l; }
  __syncthreads();
  const float mg = fmaxf(fmaxf(sm[0], sm[1]), fmaxf(sm[2], sm[3]));
  const float lg = sl[0]*__expf(sm[0]-mg) + sl[1]*__expf(sm[1]-mg)
                 + sl[2]*__expf(sm[2]-mg) + sl[3]*__expf(sm[3]-mg);
  const float scw = __expf(m - mg);
  #pragma unroll
  for (int j = 0; j < 16; ++j) sctx[wave][lane*16 + j] = cacc[j]*scw;
  __syncthreads();
  const int d = threadIdx.x * 4;
  const float4 a0 = *(const float4*)&sctx[0][d];
  const float4 a1 = *(const float4*)&sctx[1][d];
  const float4 a2 = *(const float4*)&sctx[2][d];
  const float4 a3 = *(const float4*)&sctx[3][d];
  float4 rr;
  rr.x = a0.x+a1.x+a2.x+a3.x; rr.y = a0.y+a1.y+a2.y+a3.y;
  rr.z = a0.z+a1.z+a2.z+a3.z; rr.w = a0.w+a1.w+a2.w+a3.w;
  *(float4*)(ctxpart + ((size_t)(b*C + ch))*HH + d) = rr;
  if (threadIdx.x == 0) { mpart[b*C+ch] = mg; lpart[b*C+ch] = lg; }
}

// ---------------- attention combine + ctx bf16 into concA[:,1024:2048] --------
__global__ void k_attn_fin(const float* __restrict__ mpart, const float* __restrict__ lpart,
                           const float* __restrict__ ctxpart, const float* __restrict__ energ,
                           float* __restrict__ attn, short* __restrict__ concA, int C){
  const int b = blockIdx.x, tid = threadIdx.x;
  float m = -INFINITY;
  for (int c = 0; c < C; ++c) m = fmaxf(m, mpart[b*C+c]);
  float l = 0.f;
  for (int c = 0; c < C; ++c) l += lpart[b*C+c] * __expf(mpart[b*C+c] - m);
  const float inv = 1.0f / l;
  float ax = 0.f, ay = 0.f, az = 0.f, aw = 0.f;
  for (int c = 0; c < C; ++c) {
    const float w = __expf(mpart[b*C+c] - m);
    const float* cp = ctxpart + ((size_t)(b*C+c))*HH + tid*4;
    ax += w*cp[0]; ay += w*cp[1]; az += w*cp[2]; aw += w*cp[3];
  }
  ax *= inv; ay *= inv; az *= inv; aw *= inv;
  short* ca = concA + (size_t)b*2048 + 1024 + tid*4;
  ca[0] = f2bf(ax); ca[1] = f2bf(ay); ca[2] = f2bf(az); ca[3] = f2bf(aw);
  for (int j = 0; j < 8; ++j) {
    const int s = j*256 + tid;
    attn[(size_t)b*SS + s] = __expf(energ[(size_t)b*SS + s] - m) * inv;
  }
}

extern "C" void kernel_launch(void* const* d_in, const int* in_sizes, int n_in,
                              void* d_out, int out_size, void* d_ws, size_t ws_size,
                              hipStream_t stream){
  const int*   seq  = (const int*)  d_in[0];
  const float* h0   = (const float*)d_in[1];
  const float* c0   = (const float*)d_in[2];
  const float* enc  = (const float*)d_in[3];
  const float* embW = (const float*)d_in[4];
  const float* W_ih = (const float*)d_in[5];
  const float* W_hh = (const float*)d_in[6];
  const float* b_ih = (const float*)d_in[7];
  const float* b_hh = (const float*)d_in[8];
  const float* cW   = (const float*)d_in[9];
  const float* cb   = (const float*)d_in[10];
  const float* oW   = (const float*)d_in[11];
  const float* ob   = (const float*)d_in[12];
  float* out = (float*)d_out;

  float* ws = (float*)d_ws;
  // ws layout (float offsets)
  const size_t o_energ = 0;            // 131072
  const size_t o_concA = 131072;       // 65536 (64x2048 bf16)
  const size_t o_concB = 196608;       // 32768 (64x1024 bf16)
  const size_t o_mp    = 229376;
  const size_t SKPART  = 4194304;      // 16*64*4096 fp32 partials
  int C = 32;
  for (;;) {
    size_t need = (o_mp + (size_t)64*C*2 + (size_t)64*C*1024 + SKPART) * sizeof(float);
    if (need <= ws_size || C == 1) break;
    C >>= 1;
  }
  float* energ   = ws + o_energ;
  short* concA   = (short*)(ws + o_concA);
  short* concB   = (short*)(ws + o_concB);
  float* mpart   = ws + o_mp;
  float* lpart   = mpart + (size_t)64*C;
  float* ctxpart = lpart + (size_t)64*C;
  float* skpart  = ctxpart + (size_t)64*C*1024;

  const size_t o_h = 3216448, o_c = 3281984, o_attn = 3347520;

  // gates = emb[seq]@W_ih^T + h0@W_hh^T (partials, split-K 16)
  k_gates<<<dim3(32,16), 256, 0, stream>>>(seq, embW, h0, W_ih, W_hh, skpart);
  // reduce + biases + LSTM pointwise -> h, c, concA[:, :1024] (bf16)
  k_rlstm<<<256, 256, 0, stream>>>(skpart, b_ih, b_hh, c0, out + o_h, out + o_c,
                                   concA, 16);
  // fused attention (single encoder read)
  k_attn_part<<<64*C, 256, 0, stream>>>(out + o_h, enc, energ, mpart, lpart, ctxpart, C);
  k_attn_fin<<<64, 256, 0, stream>>>(mpart, lpart, ctxpart, energ, out + o_attn, concA, C);
  // concat_out = tanh([h,ctx] @ cW^T + cb) -> bf16 (MFMA, split-K 16)
  k_mfma<<<dim3(8,16), 256, 0, stream>>>(concA, 2048, cW, 2048, skpart, 1024, 2048);
  k_reduce<<<256, 256, 0, stream>>>(skpart, cb, concB, 1024, 16);
  // logits = concat_out @ out_W^T + out_b
  k_logits<<<393, 256, 0, stream>>>(concB, oW, ob, out);
}

// Round 4
// 258.775 us; speedup vs baseline: 1.7381x; 1.0332x over previous
//
#include <hip/hip_runtime.h>
#include <hip/hip_bf16.h>
#include <math.h>

#define BB 64
#define HH 1024
#define SS 2048
#define VV 50257

typedef float f32x4 __attribute__((ext_vector_type(4)));
typedef short bf16x8 __attribute__((ext_vector_type(8)));

__device__ __forceinline__ float sigf(float x){ return 1.0f/(1.0f+__expf(-x)); }
__device__ __forceinline__ short f2bf(float f){
  __hip_bfloat16 h = __float2bfloat16(f);
  return __builtin_bit_cast(short, h);
}
__device__ __forceinline__ float bf2f(short s){
  __hip_bfloat16 h = __builtin_bit_cast(__hip_bfloat16, s);
  return __bfloat162float(h);
}

// ------ prep: A = [emb[seq] | h0] split into bf16 hi/lo pair  [64][2048] -----
__global__ void k_prep(const int* __restrict__ seq, const float* __restrict__ embW,
                       const float* __restrict__ h0,
                       short* __restrict__ Ahi, short* __restrict__ Alo){
  const int b = blockIdx.x;
  const int k = threadIdx.x * 8;     // 0..2047
  const float* src = (k < 1024) ? (embW + (size_t)seq[b]*1024 + k)
                                : (h0 + (size_t)b*1024 + (k - 1024));
  float4 v0 = *(const float4*)src;
  float4 v1 = *(const float4*)(src + 4);
  float v[8] = {v0.x,v0.y,v0.z,v0.w,v1.x,v1.y,v1.z,v1.w};
  bf16x8 hi, lo;
  #pragma unroll
  for (int j = 0; j < 8; ++j) {
    short h = f2bf(v[j]);
    hi[j] = h;
    lo[j] = f2bf(v[j] - bf2f(h));
  }
  *(bf16x8*)(Ahi + (size_t)b*2048 + k) = hi;
  *(bf16x8*)(Alo + (size_t)b*2048 + k) = lo;
}

// ------ gates GEMM via bf16-pair MFMA: partials dst[sk][64][4096] ------------
// grid (32, 16), 256 thr. K=2048 (k<1024 -> W_ih, else W_hh). 3-MFMA pair trick.
__global__ __launch_bounds__(256, 3)
void k_gates(const short* __restrict__ Ahi, const short* __restrict__ Alo,
             const float* __restrict__ W_ih, const float* __restrict__ W_hh,
             float* __restrict__ dst)
{
  const int tid = threadIdx.x;
  const int wave = tid >> 6, lane = tid & 63;
  const int r = lane & 15, g = lane >> 4;
  const int nb = blockIdx.x, sk = blockIdx.y;
  const int n0 = nb*128 + wave*32;
  const int kbase = sk*128;
  const float* Wm = (kbase < 1024) ? W_ih : W_hh;
  const int kw = (kbase < 1024) ? kbase : (kbase - 1024);

  f32x4 acc[4][2] = {};

  #pragma unroll
  for (int ks = 0; ks < 4; ++ks) {
    const int kk = kbase + ks*32 + g*8;     // A offset
    const int ko = kw   + ks*32 + g*8;      // W offset
    bf16x8 ahi[4], alo[4];
    #pragma unroll
    for (int mf = 0; mf < 4; ++mf) {
      ahi[mf] = *(const bf16x8*)(Ahi + (size_t)(mf*16 + r)*2048 + kk);
      alo[mf] = *(const bf16x8*)(Alo + (size_t)(mf*16 + r)*2048 + kk);
    }
    #pragma unroll
    for (int nf = 0; nf < 2; ++nf) {
      const int n = n0 + nf*16 + r;
      const float* wp = Wm + (size_t)n*1024 + ko;
      float4 w0 = *(const float4*)wp;
      float4 w1 = *(const float4*)(wp + 4);
      float wv[8] = {w0.x,w0.y,w0.z,w0.w,w1.x,w1.y,w1.z,w1.w};
      bf16x8 whi, wlo;
      #pragma unroll
      for (int j = 0; j < 8; ++j) {
        short h = f2bf(wv[j]);
        whi[j] = h;
        wlo[j] = f2bf(wv[j] - bf2f(h));
      }
      #pragma unroll
      for (int mf = 0; mf < 4; ++mf) {
        acc[mf][nf] = __builtin_amdgcn_mfma_f32_16x16x32_bf16(ahi[mf], whi, acc[mf][nf], 0,0,0);
        acc[mf][nf] = __builtin_amdgcn_mfma_f32_16x16x32_bf16(alo[mf], whi, acc[mf][nf], 0,0,0);
        acc[mf][nf] = __builtin_amdgcn_mfma_f32_16x16x32_bf16(ahi[mf], wlo, acc[mf][nf], 0,0,0);
      }
    }
  }

  #pragma unroll
  for (int nf = 0; nf < 2; ++nf) {
    const int n = n0 + nf*16 + r;
    #pragma unroll
    for (int mf = 0; mf < 4; ++mf)
      #pragma unroll
      for (int j = 0; j < 4; ++j)
        dst[((size_t)sk*64 + (mf*16 + g*4 + j))*4096 + n] = acc[mf][nf][j];
  }
}

// -------- fused split-K reduce + bias + LSTM pointwise -> h, c, concA[:, :1024]
__global__ void k_rlstm(const float* __restrict__ part, const float* __restrict__ b_ih,
                        const float* __restrict__ b_hh, const float* __restrict__ c0,
                        float* __restrict__ h_out, float* __restrict__ c_out,
                        short* __restrict__ concA, int SK){
  int idx = blockIdx.x*256 + threadIdx.x;    // 64*1024
  int b = idx >> 10, k = idx & 1023;
  float gi = b_ih[k]      + b_hh[k];
  float gf = b_ih[1024+k] + b_hh[1024+k];
  float gg = b_ih[2048+k] + b_hh[2048+k];
  float go = b_ih[3072+k] + b_hh[3072+k];
  const float* p = part + (size_t)b*4096 + k;
  for (int s = 0; s < SK; ++s) {
    const float* ps = p + (size_t)s*64*4096;
    gi += ps[0]; gf += ps[1024]; gg += ps[2048]; go += ps[3072];
  }
  float c = sigf(gf)*c0[idx] + sigf(gi)*tanhf(gg);
  float h = sigf(go)*tanhf(c);
  c_out[idx] = c;
  h_out[idx] = h;
  concA[(size_t)b*2048 + k] = f2bf(h);
}

// ---------------- streaming bf16 MFMA GEMM (concat): partials dst[sk][64][N] --
__global__ __launch_bounds__(256)
void k_mfma(const short* __restrict__ A, int lda,
            const float* __restrict__ W1, int ldw,
            float* __restrict__ dst, int N, int Ktot)
{
  const int tid  = threadIdx.x;
  const int wave = tid >> 6, lane = tid & 63;
  const int nb = blockIdx.x, sk = blockIdx.y, SK = gridDim.y;
  const int ksteps = Ktot >> 5;
  const int kps = ksteps / SK;
  const int k0 = sk * kps;
  const int n0 = nb*128 + wave*32;
  const int r = lane & 15, g = lane >> 4;

  f32x4 acc[4][2] = {};

  for (int ks = k0; ks < k0 + kps; ++ks) {
    const int kk = (ks << 5) + g*8;
    bf16x8 af[4];
    #pragma unroll
    for (int mf = 0; mf < 4; ++mf)
      af[mf] = *(const bf16x8*)(A + (size_t)(mf*16 + r)*lda + kk);
    #pragma unroll
    for (int nf = 0; nf < 2; ++nf) {
      const int n = n0 + nf*16 + r;
      const float* wp = W1 + (size_t)n*ldw + kk;
      float4 w0 = *(const float4*)wp;
      float4 w1 = *(const float4*)(wp + 4);
      bf16x8 bfr;
      bfr[0]=f2bf(w0.x); bfr[1]=f2bf(w0.y); bfr[2]=f2bf(w0.z); bfr[3]=f2bf(w0.w);
      bfr[4]=f2bf(w1.x); bfr[5]=f2bf(w1.y); bfr[6]=f2bf(w1.z); bfr[7]=f2bf(w1.w);
      #pragma unroll
      for (int mf = 0; mf < 4; ++mf)
        acc[mf][nf] = __builtin_amdgcn_mfma_f32_16x16x32_bf16(af[mf], bfr, acc[mf][nf], 0, 0, 0);
    }
  }

  #pragma unroll
  for (int nf = 0; nf < 2; ++nf) {
    const int n = n0 + nf*16 + r;
    #pragma unroll
    for (int mf = 0; mf < 4; ++mf)
      #pragma unroll
      for (int j = 0; j < 4; ++j)
        dst[((size_t)sk*64 + (mf*16 + g*4 + j))*N + n] = acc[mf][nf][j];
  }
}

// ---------------- split-K reduce + bias + tanh -> bf16 ------------------------
__global__ void k_reduce(const float* __restrict__ part, const float* __restrict__ bias,
                         short* __restrict__ dstb, int N, int SK){
  size_t idx = (size_t)blockIdx.x*256 + threadIdx.x;
  if (idx >= (size_t)64*N) return;
  int b = (int)(idx / N), n = (int)(idx % N);
  float v = bias[n];
  for (int s = 0; s < SK; ++s) v += part[((size_t)s*64 + b)*N + n];
  dstb[(size_t)b*N + n] = f2bf(tanhf(v));
}

// ------ logits: D[64][50257] = A_bf16[64][1024] @ oW^T + ob -------------------
// 256 thr: 4 waves = 2 col-groups x 2 K-halves; in-block K-reduce via LDS.
// Even/odd register pipeline on the W (HBM) and A (L2) streams.
__global__ __launch_bounds__(256, 3)
void k_logits(const short* __restrict__ A, const float* __restrict__ W,
              const float* __restrict__ bias, float* __restrict__ out)
{
  const int tid = threadIdx.x;
  const int wave = tid >> 6, lane = tid & 63;
  const int r = lane & 15, g = lane >> 4;
  const int cg = wave & 1, kh = wave >> 1;
  const int n0 = blockIdx.x*64 + cg*32;
  const int nA = n0 + r, nB = n0 + 16 + r;
  const int nAc = (nA < VV) ? nA : 0;
  const int nBc = (nB < VV) ? nB : 0;
  const int kb = kh * 512;

  const short* A0 = A + (size_t)r*1024       + kb + g*8;
  const short* A1 = A + (size_t)(16+r)*1024  + kb + g*8;
  const short* A2 = A + (size_t)(32+r)*1024  + kb + g*8;
  const short* A3 = A + (size_t)(48+r)*1024  + kb + g*8;
  const float* wA = W + (size_t)nAc*1024 + kb + g*8;
  const float* wB = W + (size_t)nBc*1024 + kb + g*8;

  f32x4 acc[4][2] = {};

  bf16x8 aE0,aE1,aE2,aE3, aO0,aO1,aO2,aO3;
  float4 wEA0,wEA1,wEB0,wEB1, wOA0,wOA1,wOB0,wOB1;

#define LOAD_E(KS) { const int o=(KS)*32; \
    aE0=*(const bf16x8*)(A0+o); aE1=*(const bf16x8*)(A1+o); \
    aE2=*(const bf16x8*)(A2+o); aE3=*(const bf16x8*)(A3+o); \
    wEA0=*(const float4*)(wA+o); wEA1=*(const float4*)(wA+o+4); \
    wEB0=*(const float4*)(wB+o); wEB1=*(const float4*)(wB+o+4); }
#define LOAD_O(KS) { const int o=(KS)*32; \
    aO0=*(const bf16x8*)(A0+o); aO1=*(const bf16x8*)(A1+o); \
    aO2=*(const bf16x8*)(A2+o); aO3=*(const bf16x8*)(A3+o); \
    wOA0=*(const float4*)(wA+o); wOA1=*(const float4*)(wA+o+4); \
    wOB0=*(const float4*)(wB+o); wOB1=*(const float4*)(wB+o+4); }
#define CVT(bdst, w0, w1) { \
    bdst[0]=f2bf(w0.x); bdst[1]=f2bf(w0.y); bdst[2]=f2bf(w0.z); bdst[3]=f2bf(w0.w); \
    bdst[4]=f2bf(w1.x); bdst[5]=f2bf(w1.y); bdst[6]=f2bf(w1.z); bdst[7]=f2bf(w1.w); }
#define MM(a0_,a1_,a2_,a3_,bA_,bB_) { \
    acc[0][0]=__builtin_amdgcn_mfma_f32_16x16x32_bf16(a0_,bA_,acc[0][0],0,0,0); \
    acc[1][0]=__builtin_amdgcn_mfma_f32_16x16x32_bf16(a1_,bA_,acc[1][0],0,0,0); \
    acc[2][0]=__builtin_amdgcn_mfma_f32_16x16x32_bf16(a2_,bA_,acc[2][0],0,0,0); \
    acc[3][0]=__builtin_amdgcn_mfma_f32_16x16x32_bf16(a3_,bA_,acc[3][0],0,0,0); \
    acc[0][1]=__builtin_amdgcn_mfma_f32_16x16x32_bf16(a0_,bB_,acc[0][1],0,0,0); \
    acc[1][1]=__builtin_amdgcn_mfma_f32_16x16x32_bf16(a1_,bB_,acc[1][1],0,0,0); \
    acc[2][1]=__builtin_amdgcn_mfma_f32_16x16x32_bf16(a2_,bB_,acc[2][1],0,0,0); \
    acc[3][1]=__builtin_amdgcn_mfma_f32_16x16x32_bf16(a3_,bB_,acc[3][1],0,0,0); }

  LOAD_E(0);
  LOAD_O(1);
  #pragma unroll
  for (int it = 0; it < 8; ++it) {
    const int ks = it*2;
    {
      bf16x8 bA, bB;
      CVT(bA, wEA0, wEA1); CVT(bB, wEB0, wEB1);
      bf16x8 ca0=aE0, ca1=aE1, ca2=aE2, ca3=aE3;
      if (it < 7) LOAD_E(ks+2);
      MM(ca0,ca1,ca2,ca3,bA,bB);
    }
    {
      bf16x8 bA, bB;
      CVT(bA, wOA0, wOA1); CVT(bB, wOB0, wOB1);
      bf16x8 ca0=aO0, ca1=aO1, ca2=aO2, ca3=aO3;
      if (it < 7) LOAD_O(ks+3);
      MM(ca0,ca1,ca2,ca3,bA,bB);
    }
  }
#undef LOAD_E
#undef LOAD_O
#undef CVT
#undef MM

  // in-block K-reduction: kh==1 waves deposit, kh==0 waves combine + write
  __shared__ float red[2][32][64];
  if (kh) {
    #pragma unroll
    for (int nf = 0; nf < 2; ++nf)
      #pragma unroll
      for (int mf = 0; mf < 4; ++mf)
        #pragma unroll
        for (int j = 0; j < 4; ++j)
          red[cg][nf*16 + mf*4 + j][lane] = acc[mf][nf][j];
  }
  __syncthreads();
  if (!kh) {
    #pragma unroll
    for (int nf = 0; nf < 2; ++nf) {
      const int n = n0 + nf*16 + r;
      if (n < VV) {
        const float bv = bias[n];
        #pragma unroll
        for (int mf = 0; mf < 4; ++mf)
          #pragma unroll
          for (int j = 0; j < 4; ++j)
            out[(size_t)(mf*16 + g*4 + j)*VV + n] =
                acc[mf][nf][j] + red[cg][nf*16 + mf*4 + j][lane] + bv;
      }
    }
  }
}

// ---------------- attention pass 1: wave-per-2-rows, no barriers in loop ------
__global__ __launch_bounds__(256)
void k_attn_part(const float* __restrict__ h, const float* __restrict__ enc,
                 float* __restrict__ energ, float* __restrict__ mpart,
                 float* __restrict__ lpart, float* __restrict__ ctxpart, int C){
  const int b  = blockIdx.x & 63;
  const int ch = blockIdx.x >> 6;
  const int wave = threadIdx.x >> 6;
  const int lane = threadIdx.x & 63;
  const int rows = SS / C;
  const int rpw  = rows >> 2;
  const int sw = ch*rows + wave*rpw;

  float4 hv0, hv1, hv2, hv3;
  {
    const float* hb = h + (size_t)b*HH + lane*16;
    hv0 = *(const float4*)(hb);   hv1 = *(const float4*)(hb+4);
    hv2 = *(const float4*)(hb+8); hv3 = *(const float4*)(hb+12);
  }
  float m = -INFINITY, l = 0.f;
  float cacc[16];
  #pragma unroll
  for (int j = 0; j < 16; ++j) cacc[j] = 0.f;

  for (int i = 0; i < rpw; i += 2) {
    const float* ep = enc + ((size_t)(sw+i)*BB + b)*HH + lane*16;
    const float* fp = ep + (size_t)BB*HH;
    const float4 e0 = *(const float4*)(ep);
    const float4 e1 = *(const float4*)(ep+4);
    const float4 e2 = *(const float4*)(ep+8);
    const float4 e3 = *(const float4*)(ep+12);
    const float4 f0 = *(const float4*)(fp);
    const float4 f1 = *(const float4*)(fp+4);
    const float4 f2 = *(const float4*)(fp+8);
    const float4 f3 = *(const float4*)(fp+12);
    float p = hv0.x*e0.x + hv0.y*e0.y + hv0.z*e0.z + hv0.w*e0.w
            + hv1.x*e1.x + hv1.y*e1.y + hv1.z*e1.z + hv1.w*e1.w
            + hv2.x*e2.x + hv2.y*e2.y + hv2.z*e2.z + hv2.w*e2.w
            + hv3.x*e3.x + hv3.y*e3.y + hv3.z*e3.z + hv3.w*e3.w;
    float q = hv0.x*f0.x + hv0.y*f0.y + hv0.z*f0.z + hv0.w*f0.w
            + hv1.x*f1.x + hv1.y*f1.y + hv1.z*f1.z + hv1.w*f1.w
            + hv2.x*f2.x + hv2.y*f2.y + hv2.z*f2.z + hv2.w*f2.w
            + hv3.x*f3.x + hv3.y*f3.y + hv3.z*f3.z + hv3.w*f3.w;
    p += __shfl_xor(p, 1);  q += __shfl_xor(q, 1);
    p += __shfl_xor(p, 2);  q += __shfl_xor(q, 2);
    p += __shfl_xor(p, 4);  q += __shfl_xor(q, 4);
    p += __shfl_xor(p, 8);  q += __shfl_xor(q, 8);
    p += __shfl_xor(p, 16); q += __shfl_xor(q, 16);
    p += __shfl_xor(p, 32); q += __shfl_xor(q, 32);
    if (lane == 0) {
      float2 pq; pq.x = p; pq.y = q;
      *(float2*)(energ + (size_t)b*SS + sw + i) = pq;
    }
    const float mn = fmaxf(fmaxf(m, p), q);
    const float sc = __expf(m - mn);
    const float pe = __expf(p - mn);
    const float qe = __expf(q - mn);
    l = l*sc + pe + qe;
    cacc[0] = cacc[0]*sc + pe*e0.x + qe*f0.x;
    cacc[1] = cacc[1]*sc + pe*e0.y + qe*f0.y;
    cacc[2] = cacc[2]*sc + pe*e0.z + qe*f0.z;
    cacc[3] = cacc[3]*sc + pe*e0.w + qe*f0.w;
    cacc[4] = cacc[4]*sc + pe*e1.x + qe*f1.x;
    cacc[5] = cacc[5]*sc + pe*e1.y + qe*f1.y;
    cacc[6] = cacc[6]*sc + pe*e1.z + qe*f1.z;
    cacc[7] = cacc[7]*sc + pe*e1.w + qe*f1.w;
    cacc[8] = cacc[8]*sc + pe*e2.x + qe*f2.x;
    cacc[9] = cacc[9]*sc + pe*e2.y + qe*f2.y;
    cacc[10] = cacc[10]*sc + pe*e2.z + qe*f2.z;
    cacc[11] = cacc[11]*sc + pe*e2.w + qe*f2.w;
    cacc[12] = cacc[12]*sc + pe*e3.x + qe*f3.x;
    cacc[13] = cacc[13]*sc + pe*e3.y + qe*f3.y;
    cacc[14] = cacc[14]*sc + pe*e3.z + qe*f3.z;
    cacc[15] = cacc[15]*sc + pe*e3.w + qe*f3.w;
    m = mn;
  }

  __shared__ float sm[4], sl[4];
  __shared__ float sctx[4][1024];
  if (lane == 0) { sm[wave] = m; sl[wave] = l; }
  __syncthreads();
  const float mg = fmaxf(fmaxf(sm[0], sm[1]), fmaxf(sm[2], sm[3]));
  const float lg = sl[0]*__expf(sm[0]-mg) + sl[1]*__expf(sm[1]-mg)
                 + sl[2]*__expf(sm[2]-mg) + sl[3]*__expf(sm[3]-mg);
  const float scw = __expf(m - mg);
  #pragma unroll
  for (int j = 0; j < 16; ++j) sctx[wave][lane*16 + j] = cacc[j]*scw;
  __syncthreads();
  const int d = threadIdx.x * 4;
  const float4 a0 = *(const float4*)&sctx[0][d];
  const float4 a1 = *(const float4*)&sctx[1][d];
  const float4 a2 = *(const float4*)&sctx[2][d];
  const float4 a3 = *(const float4*)&sctx[3][d];
  float4 rr;
  rr.x = a0.x+a1.x+a2.x+a3.x; rr.y = a0.y+a1.y+a2.y+a3.y;
  rr.z = a0.z+a1.z+a2.z+a3.z; rr.w = a0.w+a1.w+a2.w+a3.w;
  *(float4*)(ctxpart + ((size_t)(b*C + ch))*HH + d) = rr;
  if (threadIdx.x == 0) { mpart[b*C+ch] = mg; lpart[b*C+ch] = lg; }
}

// ---------------- attention combine + ctx bf16 into concA[:,1024:2048] --------
__global__ void k_attn_fin(const float* __restrict__ mpart, const float* __restrict__ lpart,
                           const float* __restrict__ ctxpart, const float* __restrict__ energ,
                           float* __restrict__ attn, short* __restrict__ concA, int C){
  const int b = blockIdx.x, tid = threadIdx.x;
  float m = -INFINITY;
  for (int c = 0; c < C; ++c) m = fmaxf(m, mpart[b*C+c]);
  float l = 0.f;
  for (int c = 0; c < C; ++c) l += lpart[b*C+c] * __expf(mpart[b*C+c] - m);
  const float inv = 1.0f / l;
  float ax = 0.f, ay = 0.f, az = 0.f, aw = 0.f;
  for (int c = 0; c < C; ++c) {
    const float w = __expf(mpart[b*C+c] - m);
    const float* cp = ctxpart + ((size_t)(b*C+c))*HH + tid*4;
    ax += w*cp[0]; ay += w*cp[1]; az += w*cp[2]; aw += w*cp[3];
  }
  ax *= inv; ay *= inv; az *= inv; aw *= inv;
  short* ca = concA + (size_t)b*2048 + 1024 + tid*4;
  ca[0] = f2bf(ax); ca[1] = f2bf(ay); ca[2] = f2bf(az); ca[3] = f2bf(aw);
  for (int j = 0; j < 8; ++j) {
    const int s = j*256 + tid;
    attn[(size_t)b*SS + s] = __expf(energ[(size_t)b*SS + s] - m) * inv;
  }
}

extern "C" void kernel_launch(void* const* d_in, const int* in_sizes, int n_in,
                              void* d_out, int out_size, void* d_ws, size_t ws_size,
                              hipStream_t stream){
  const int*   seq  = (const int*)  d_in[0];
  const float* h0   = (const float*)d_in[1];
  const float* c0   = (const float*)d_in[2];
  const float* enc  = (const float*)d_in[3];
  const float* embW = (const float*)d_in[4];
  const float* W_ih = (const float*)d_in[5];
  const float* W_hh = (const float*)d_in[6];
  const float* b_ih = (const float*)d_in[7];
  const float* b_hh = (const float*)d_in[8];
  const float* cW   = (const float*)d_in[9];
  const float* cb   = (const float*)d_in[10];
  const float* oW   = (const float*)d_in[11];
  const float* ob   = (const float*)d_in[12];
  float* out = (float*)d_out;

  float* ws = (float*)d_ws;
  // ws layout (float offsets)
  const size_t o_energ = 0;            // 131072
  const size_t o_concA = 131072;       // 65536  (64x2048 bf16)
  const size_t o_concB = 196608;       // 32768  (64x1024 bf16)
  const size_t o_Ahi   = 229376;       // 65536  (64x2048 bf16)
  const size_t o_Alo   = 294912;       // 65536
  const size_t o_mp    = 360448;
  const size_t SKPART  = 4194304;      // 16*64*4096 fp32 partials
  int C = 32;
  for (;;) {
    size_t need = (o_mp + (size_t)64*C*2 + (size_t)64*C*1024 + SKPART) * sizeof(float);
    if (need <= ws_size || C == 1) break;
    C >>= 1;
  }
  float* energ   = ws + o_energ;
  short* concA   = (short*)(ws + o_concA);
  short* concB   = (short*)(ws + o_concB);
  short* Ahi     = (short*)(ws + o_Ahi);
  short* Alo     = (short*)(ws + o_Alo);
  float* mpart   = ws + o_mp;
  float* lpart   = mpart + (size_t)64*C;
  float* ctxpart = lpart + (size_t)64*C;
  float* skpart  = ctxpart + (size_t)64*C*1024;

  const size_t o_h = 3216448, o_c = 3281984, o_attn = 3347520;

  // A = [emb[seq] | h0] as bf16 hi/lo pair
  k_prep<<<64, 256, 0, stream>>>(seq, embW, h0, Ahi, Alo);
  // gates partials via pair-MFMA (split-K 16)
  k_gates<<<dim3(32,16), 256, 0, stream>>>(Ahi, Alo, W_ih, W_hh, skpart);
  // reduce + biases + LSTM pointwise -> h, c, concA[:, :1024] (bf16)
  k_rlstm<<<256, 256, 0, stream>>>(skpart, b_ih, b_hh, c0, out + o_h, out + o_c,
                                   concA, 16);
  // fused attention (single encoder read)
  k_attn_part<<<64*C, 256, 0, stream>>>(out + o_h, enc, energ, mpart, lpart, ctxpart, C);
  k_attn_fin<<<64, 256, 0, stream>>>(mpart, lpart, ctxpart, energ, out + o_attn, concA, C);
  // concat_out = tanh([h,ctx] @ cW^T + cb) -> bf16 (MFMA, split-K 16)
  k_mfma<<<dim3(8,16), 256, 0, stream>>>(concA, 2048, cW, 2048, skpart, 1024, 2048);
  k_reduce<<<256, 256, 0, stream>>>(skpart, cb, concB, 1024, 16);
  // logits = concat_out @ out_W^T + out_b  (786 blocks, in-block split-K)
  k_logits<<<786, 256, 0, stream>>>(concB, oW, ob, out);
}